// Round 17
// baseline (3107.048 us; speedup 1.0000x reference)
//
#include <hip/hip_runtime.h>
#include <cstdint>
#include <cstddef>

typedef _Float16 f16x2 __attribute__((ext_vector_type(2)));
typedef _Float16 half4 __attribute__((ext_vector_type(4)));
typedef _Float16 half8 __attribute__((ext_vector_type(8)));
typedef float f32x4 __attribute__((ext_vector_type(4)));

static constexpr int BB = 64;    // batch
static constexpr int TT = 1024;  // time steps
static constexpr int FF = 512;   // input features
static constexpr int UU = 256;   // hidden units per direction
static constexpr int NZ = 1024;  // 4*UU gate width

static constexpr size_t LSTM_SHBYTES = 90112;   // force 1 block/CU (160KiB LDS pool)

__device__ __forceinline__ f16x2 bc16(unsigned int v) { return __builtin_bit_cast(f16x2, v); }

__device__ __forceinline__ void st_u32_rlx(unsigned int* p, unsigned int v)
{
    __hip_atomic_store(p, v, __ATOMIC_RELAXED, __HIP_MEMORY_SCOPE_AGENT);
}
__device__ __forceinline__ unsigned int ld_u32_rlx(const unsigned int* p)
{
    return __hip_atomic_load(p, __ATOMIC_RELAXED, __HIP_MEMORY_SCOPE_AGENT);
}

// Raw barrier: drains LDS ops only; global loads (vmcnt) stay in flight.
__device__ __forceinline__ void bar_lgkm()
{
    asm volatile("s_waitcnt lgkmcnt(0)\n\ts_barrier" ::: "memory");
}

// ---------------------------------------------------------------------------
// Cast x fp32 -> f16 (flat)
// ---------------------------------------------------------------------------
__global__ __launch_bounds__(256) void enc_cast_x(
    const float* __restrict__ x, _Float16* __restrict__ x16, int n4)
{
    int stride = gridDim.x * 256;
    for (int i = blockIdx.x * 256 + threadIdx.x; i < n4; i += stride) {
        float4 v = ((const float4*)x)[i];
        half4 o;
        o.x = (_Float16)v.x; o.y = (_Float16)v.y;
        o.z = (_Float16)v.z; o.w = (_Float16)v.w;
        ((half4*)x16)[i] = o;
    }
}

// ---------------------------------------------------------------------------
// W [512,1024] fp32 -> WT [dir][1024][512] f16 (transposed)
// ---------------------------------------------------------------------------
__global__ __launch_bounds__(256) void enc_cast_wt(
    const float* __restrict__ Wf, const float* __restrict__ Wb,
    _Float16* __restrict__ WT)
{
    __shared__ float tile[64][65];
    const int t = threadIdx.x;
    const int k0 = blockIdx.x * 64;
    const int n0 = blockIdx.y * 64;
    const int d = blockIdx.z;
    const float* W = d ? Wb : Wf;
    _Float16* WTd = WT + (size_t)d * NZ * FF;
#pragma unroll
    for (int p = 0; p < 16; ++p) {
        int idx = p * 256 + t;
        int r = idx >> 6, c = idx & 63;
        tile[r][c] = W[(size_t)(k0 + r) * NZ + n0 + c];
    }
    __syncthreads();
#pragma unroll
    for (int p = 0; p < 16; ++p) {
        int idx = p * 256 + t;
        int r = idx >> 6, c = idx & 63;
        WTd[(size_t)(n0 + r) * FF + k0 + c] = (_Float16)tile[c][r];
    }
}

// ---------------------------------------------------------------------------
// Pack U into per-thread 4-way-k-split layout:
// Upkr2[(d*128 + k2)*256 + j] = uint4 of 4 gate words;
// word g = { U_d[2*k2][g*256+j], U_d[2*k2+1][g*256+j] } as f16x2.
// ---------------------------------------------------------------------------
__global__ __launch_bounds__(256) void enc_pack_u16v2(
    const float* __restrict__ Uf, const float* __restrict__ Ub,
    uint4* __restrict__ Upkr2)
{
    int idx = blockIdx.x * 256 + threadIdx.x;     // 0 .. 65535
    if (idx >= 2 * 128 * 256) return;
    int d  = idx >> 15;
    int k2 = (idx >> 8) & 127;
    int j  = idx & 255;
    int k = 2 * k2;
    const float* Ud = d ? Ub : Uf;
    unsigned int w[4];
#pragma unroll
    for (int g = 0; g < 4; ++g) {
        f16x2 h;
        h.x = (_Float16)Ud[(size_t)k * NZ + g * 256 + j];
        h.y = (_Float16)Ud[(size_t)(k + 1) * NZ + g * 256 + j];
        w[g] = __builtin_bit_cast(unsigned int, h);
    }
    Upkr2[idx] = make_uint4(w[0], w[1], w[2], w[3]);
}

__global__ __launch_bounds__(256) void enc_zero(float* __restrict__ p, int n)
{
    int i = blockIdx.x * 256 + threadIdx.x;
    if (i < n) p[i] = 0.f;
}

// ---------------------------------------------------------------------------
// MFMA GEMM: xz16[r, n] = x16_row(r) . W_d[:, n] + b_d[n]   (unchanged)
// ---------------------------------------------------------------------------
__global__ __launch_bounds__(256) void enc_gemm16(
    const _Float16* __restrict__ x16, const _Float16* __restrict__ WT,
    const float* __restrict__ bf, const float* __restrict__ bb,
    _Float16* __restrict__ xz16, int c0, int CT)
{
    __shared__ __align__(16) _Float16 Ash[128][40];
    __shared__ __align__(16) _Float16 Bsh[128][40];

    const int t = threadIdx.x;
    const int r0 = blockIdx.x * 128;
    const int n0 = blockIdx.y * 128;
    const int MperD = BB * CT;
    const int d = r0 / MperD;

    const int srow = t >> 2;
    const int koff = (t & 3) * 8;

    auto xrowptr = [&](int r) -> const _Float16* {
        int rd = r - d * MperD;
        int b = rd / CT;
        int tl = rd - b * CT;
        int tsrc = d ? (TT - 1 - (c0 + tl)) : (c0 + tl);
        return x16 + ((size_t)b * TT + tsrc) * FF;
    };
    const _Float16* ap0 = xrowptr(r0 + srow);
    const _Float16* ap1 = xrowptr(r0 + 64 + srow);
    const _Float16* wp0 = WT + (size_t)(d * NZ + n0 + srow) * FF;
    const _Float16* wp1 = wp0 + (size_t)64 * FF;

    const int lane = t & 63;
    const int w = t >> 6;
    const int wm = w >> 1, wn = w & 1;
    const int l15 = lane & 15;
    const int kq = (lane >> 4) * 8;

    f32x4 acc[4][4];
#pragma unroll
    for (int i = 0; i < 4; ++i)
#pragma unroll
        for (int j = 0; j < 4; ++j) acc[i][j] = (f32x4)0.f;

    for (int ks = 0; ks < FF / 32; ++ks) {
        const int k0 = ks * 32;
        uint4 av0 = *(const uint4*)(ap0 + k0 + koff);
        uint4 av1 = *(const uint4*)(ap1 + k0 + koff);
        uint4 bv0 = *(const uint4*)(wp0 + k0 + koff);
        uint4 bv1 = *(const uint4*)(wp1 + k0 + koff);
        __syncthreads();
        *(uint4*)&Ash[srow][koff]      = av0;
        *(uint4*)&Ash[64 + srow][koff] = av1;
        *(uint4*)&Bsh[srow][koff]      = bv0;
        *(uint4*)&Bsh[64 + srow][koff] = bv1;
        __syncthreads();

        half8 af[4], bfr[4];
#pragma unroll
        for (int mf = 0; mf < 4; ++mf)
            af[mf] = *(const half8*)&Ash[wm * 64 + mf * 16 + l15][kq];
#pragma unroll
        for (int nf = 0; nf < 4; ++nf)
            bfr[nf] = *(const half8*)&Bsh[wn * 64 + nf * 16 + l15][kq];
#pragma unroll
        for (int mf = 0; mf < 4; ++mf)
#pragma unroll
            for (int nf = 0; nf < 4; ++nf)
                acc[mf][nf] = __builtin_amdgcn_mfma_f32_16x16x32_f16(
                    af[mf], bfr[nf], acc[mf][nf], 0, 0, 0);
    }

    const float* bd = d ? bb : bf;
    const int rbase = r0 + wm * 64;
    const int cbase = n0 + wn * 64;
#pragma unroll
    for (int nf = 0; nf < 4; ++nf) {
        const int cc = cbase + nf * 16 + l15;
        const float bia = bd[cc];
#pragma unroll
        for (int mf = 0; mf < 4; ++mf) {
#pragma unroll
            for (int rg = 0; rg < 4; ++rg) {
                int rr = rbase + mf * 16 + (lane >> 4) * 4 + rg;
                xz16[(size_t)rr * NZ + cc] = (_Float16)(acc[mf][nf][rg] + bia);
            }
        }
    }
}

// ---------------------------------------------------------------------------
// Dual-chain split recurrence: 128 blocks = (jh = beta>>6) x (pair p = beta&63).
// Chains cA = 2p, cB = 2p+1 (same direction -> SAME U slice, shared registers).
// Per chain, the protocol and phase structure are EXACTLY R8's (proven):
//   ph1: own-half dots || isx finalizes partner h (tag = previous step)
//   ph2: partner-half dots
//   ph3: s==0 reduce+gates+tagged publish+out
// Interleaving A then B per iteration puts a full chain-half (~1000+ cyc) of
// compute between each publish and its consumption on the partner block,
// hiding the MALL round trip (R16 lesson: cross-XCD visibility is MALL-only).
// Prefetch slots are now timing-valid: A's next word sampled at ph3B
// (partner published it ~half an iteration earlier); B's word at ph3A.
// hbuf word: [(step&1)][jh*128 + chain][jl], tag = (step<<16)|f16(h).
// Deadlock-free by the R7 induction (waits reference the PREVIOUS step only).
// ---------------------------------------------------------------------------
__device__ __forceinline__ float sigm_f(float xv)
{
    return 1.0f / (1.0f + __expf(-xv));
}
__device__ __forceinline__ float tanh_f(float xv)
{
    return 2.0f / (1.0f + __expf(-2.0f * xv)) - 1.0f;
}

__global__ __launch_bounds__(512, 2) void enc_lstm_dual(
    const _Float16* __restrict__ xz16, const uint4* __restrict__ Upkr2,
    float* __restrict__ hstate, float* __restrict__ cstate,
    unsigned int* __restrict__ hbuf,
    float* __restrict__ out, int c0, int CT)
{
    extern __shared__ char smem2[];
    float4*    partsA = (float4*)smem2;                  // 3*128*16 used
    float4*    partsB = (float4*)(smem2 + 6144);
    _Float16*  hshA   = (_Float16*)(smem2 + 12288);      // 512 B
    _Float16*  hshB   = (_Float16*)(smem2 + 12800);      // 512 B
    uint4*     hshqA  = (uint4*)hshA;
    uint4*     hshqB  = (uint4*)hshB;

    const int t  = threadIdx.x;
    const int s  = t >> 7;          // k-quarter 0..3
    const int jl = t & 127;
    const int beta = blockIdx.x;
    const int jh = beta >> 6;                          // j-half
    const int p  = beta & 63;                          // chain pair
    const int cA = 2 * p;
    const int cB = 2 * p + 1;
    const int d  = cA >> 6;                            // same for cB
    const int bA = cA & 63;
    const int bB = cB & 63;
    const int j  = jh * 128 + jl;
    const bool own = ((s >> 1) == jh);    // k-range uses own h-half
    const bool isx = (s == (jh ? 1 : 2)); // exchange group

    // ---- persistent U: 32 k2-pairs x 4 gates, shared by both chains ----
    const uint4* Uq = Upkr2 + ((size_t)d * 128 + s * 32) * 256 + j;
    f16x2 ureg[32][4];
#pragma unroll
    for (int m = 0; m < 32; ++m) {
        uint4 qv = Uq[(size_t)m * 256];
        ureg[m][0] = bc16(qv.x);
        ureg[m][1] = bc16(qv.y);
        ureg[m][2] = bc16(qv.z);
        ureg[m][3] = bc16(qv.w);
    }

    // ---- state init ----
    float crA = 0.f, hnA = 0.f, crB = 0.f, hnB = 0.f;
    if (s == 0) {
        crA = cstate[(size_t)cA * UU + j];
        crB = cstate[(size_t)cB * UU + j];
    }
    if (t < 256) {
        hshA[t] = (_Float16)hstate[(size_t)cA * UU + t];
        hshB[t] = (_Float16)hstate[(size_t)cB * UU + t];
    }
    __syncthreads();

    const _Float16* xzrowA = xz16 + (size_t)cA * CT * NZ;
    const _Float16* xzrowB = xz16 + (size_t)cB * CT * NZ;
    float* outbA = out + (size_t)bA * TT * (2 * UU) + d * UU;
    float* outbB = out + (size_t)bB * TT * (2 * UU) + d * UU;

    // ---- pre-loop prefetches ----
    unsigned short xa0 = 0, xa1 = 0, xa2 = 0, xa3 = 0;
    unsigned short xb0 = 0, xb1 = 0, xb2 = 0, xb3 = 0;
    if (s == 0) {
        const unsigned short* pA = (const unsigned short*)xzrowA + j;
        xa0 = pA[0]; xa1 = pA[256]; xa2 = pA[512]; xa3 = pA[768];
        const unsigned short* pB = (const unsigned short*)xzrowB + j;
        xb0 = pB[0]; xb1 = pB[256]; xb2 = pB[512]; xb3 = pB[768];
    }
    unsigned int prefA = 0, prefB = 0;   // tag 0 never matches a real htag

    auto dot4 = [&](const uint4* hq_base, float& a0, float& a1, float& a2, float& a3) {
#pragma unroll
        for (int r = 0; r < 8; ++r) {
            uint4 hq = hq_base[s * 8 + r];         // broadcast read
            f16x2 hw[4] = {bc16(hq.x), bc16(hq.y), bc16(hq.z), bc16(hq.w)};
#pragma unroll
            for (int q = 0; q < 4; ++q) {
                const int m = r * 4 + q;
                a0 = __builtin_amdgcn_fdot2(hw[q], ureg[m][0], a0, false);
                a1 = __builtin_amdgcn_fdot2(hw[q], ureg[m][1], a1, false);
                a2 = __builtin_amdgcn_fdot2(hw[q], ureg[m][2], a2, false);
                a3 = __builtin_amdgcn_fdot2(hw[q], ureg[m][3], a3, false);
            }
        }
    };

    for (int tl = 0; tl < CT; ++tl) {
        const int step = c0 + tl + 1;   // h produced this iteration
        const int htag = c0 + tl;       // partner h consumed this iteration

        // ==================== chain A ====================
        float a0 = 0.f, a1 = 0.f, a2 = 0.f, a3 = 0.f;
        if (own) {
            dot4(hshqA, a0, a1, a2, a3);
            if (s) partsA[(s - 1) * 128 + jl] = make_float4(a0, a1, a2, a3);
        }
        if (isx && tl > 0) {
            const unsigned int* pp =
                &hbuf[((size_t)(htag & 1) * 256 + (1 - jh) * 128 + cA) * 128 + jl];
            unsigned int v = prefA;
            while ((v >> 16) != (unsigned int)htag)
                v = ld_u32_rlx(pp);
            hshA[(1 - jh) * 128 + jl] =
                __builtin_bit_cast(_Float16, (unsigned short)(v & 0xffffu));
        }
        bar_lgkm();                                // A-bar1: partner h in hshA

        if (!own) {
            dot4(hshqA, a0, a1, a2, a3);
            if (s) partsA[(s - 1) * 128 + jl] = make_float4(a0, a1, a2, a3);
        }
        bar_lgkm();                                // A-bar2: partials ready

        if (s == 0) {
            float4 p1 = partsA[jl], p2 = partsA[128 + jl], p3 = partsA[256 + jl];
            float zi = a0 + p1.x + p2.x + p3.x
                     + (float)__builtin_bit_cast(_Float16, xa0);
            float zf = a1 + p1.y + p2.y + p3.y
                     + (float)__builtin_bit_cast(_Float16, xa1);
            float zg = a2 + p1.z + p2.z + p3.z
                     + (float)__builtin_bit_cast(_Float16, xa2);
            float zo = a3 + p1.w + p2.w + p3.w
                     + (float)__builtin_bit_cast(_Float16, xa3);
            float ig = sigm_f(zi), fg = sigm_f(zf), gg = tanh_f(zg), og = sigm_f(zo);
            crA = fg * crA + ig * gg;
            hnA = og * tanh_f(crA);
            _Float16 h16 = (_Float16)hnA;
            st_u32_rlx(&hbuf[((size_t)(step & 1) * 256 + jh * 128 + cA) * 128 + jl],
                       ((unsigned int)step << 16)
                       | (unsigned int)__builtin_bit_cast(unsigned short, h16));
            hshA[j] = h16;
            int tsrc = d ? (TT - 1 - (c0 + tl)) : (c0 + tl);
            outbA[(size_t)tsrc * (2 * UU) + j] = hnA;
            int tn = (tl + 1 < CT) ? tl + 1 : tl;
            const unsigned short* pn =
                (const unsigned short*)(xzrowA + (size_t)tn * NZ) + j;
            xa0 = pn[0]; xa1 = pn[256]; xa2 = pn[512]; xa3 = pn[768];
        }
        if (isx) {
            // sample B's word for THIS iteration (partner published it at its
            // previous ph3B, ~a full A-half ago -> likely valid already)
            prefB = ld_u32_rlx(
                &hbuf[((size_t)(htag & 1) * 256 + (1 - jh) * 128 + cB) * 128 + jl]);
        }
        bar_lgkm();                                // A-bar3: hshA own half updated

        // ==================== chain B ====================
        float e0 = 0.f, e1 = 0.f, e2 = 0.f, e3 = 0.f;
        if (own) {
            dot4(hshqB, e0, e1, e2, e3);
            if (s) partsB[(s - 1) * 128 + jl] = make_float4(e0, e1, e2, e3);
        }
        if (isx && tl > 0) {
            const unsigned int* pp =
                &hbuf[((size_t)(htag & 1) * 256 + (1 - jh) * 128 + cB) * 128 + jl];
            unsigned int v = prefB;
            while ((v >> 16) != (unsigned int)htag)
                v = ld_u32_rlx(pp);
            hshB[(1 - jh) * 128 + jl] =
                __builtin_bit_cast(_Float16, (unsigned short)(v & 0xffffu));
        }
        bar_lgkm();                                // B-bar1: partner h in hshB

        if (!own) {
            dot4(hshqB, e0, e1, e2, e3);
            if (s) partsB[(s - 1) * 128 + jl] = make_float4(e0, e1, e2, e3);
        }
        bar_lgkm();                                // B-bar2: partials ready

        if (s == 0) {
            float4 p1 = partsB[jl], p2 = partsB[128 + jl], p3 = partsB[256 + jl];
            float zi = e0 + p1.x + p2.x + p3.x
                     + (float)__builtin_bit_cast(_Float16, xb0);
            float zf = e1 + p1.y + p2.y + p3.y
                     + (float)__builtin_bit_cast(_Float16, xb1);
            float zg = e2 + p1.z + p2.z + p3.z
                     + (float)__builtin_bit_cast(_Float16, xb2);
            float zo = e3 + p1.w + p2.w + p3.w
                     + (float)__builtin_bit_cast(_Float16, xb3);
            float ig = sigm_f(zi), fg = sigm_f(zf), gg = tanh_f(zg), og = sigm_f(zo);
            crB = fg * crB + ig * gg;
            hnB = og * tanh_f(crB);
            _Float16 h16 = (_Float16)hnB;
            st_u32_rlx(&hbuf[((size_t)(step & 1) * 256 + jh * 128 + cB) * 128 + jl],
                       ((unsigned int)step << 16)
                       | (unsigned int)__builtin_bit_cast(unsigned short, h16));
            hshB[j] = h16;
            int tsrc = d ? (TT - 1 - (c0 + tl)) : (c0 + tl);
            outbB[(size_t)tsrc * (2 * UU) + j] = hnB;
            int tn = (tl + 1 < CT) ? tl + 1 : tl;
            const unsigned short* pn =
                (const unsigned short*)(xzrowB + (size_t)tn * NZ) + j;
            xb0 = pn[0]; xb1 = pn[256]; xb2 = pn[512]; xb3 = pn[768];
        }
        if (isx) {
            // sample A's word for the NEXT iteration (tag = step); partner
            // published it at its ph3A earlier this iteration -> likely valid
            prefA = ld_u32_rlx(
                &hbuf[((size_t)(step & 1) * 256 + (1 - jh) * 128 + cA) * 128 + jl]);
        }
        bar_lgkm();                                // B-bar3: hshB own half updated
    }

    if (s == 0) {
        hstate[(size_t)cA * UU + j] = hnA;
        cstate[(size_t)cA * UU + j] = crA;
        hstate[(size_t)cB * UU + j] = hnB;
        cstate[(size_t)cB * UU + j] = crB;
    }
}

// ---------------------------------------------------------------------------
// Final h/c copy into d_out tail sections
// ---------------------------------------------------------------------------
__global__ __launch_bounds__(256) void enc_final(
    const float* __restrict__ hstate, const float* __restrict__ cstate,
    float* __restrict__ out)
{
    int idx = blockIdx.x * 256 + threadIdx.x;
    if (idx >= 2 * BB * UU) return;
    int d = idx / (BB * UU);
    int rem = idx - d * (BB * UU);
    int b = rem / UU;
    int j = rem - b * UU;
    size_t OUT_H = (size_t)BB * TT * (2 * UU);
    size_t HSZ = (size_t)BB * (2 * UU);
    out[OUT_H + (size_t)b * (2 * UU) + d * UU + j] = hstate[idx];
    out[OUT_H + HSZ + (size_t)b * (2 * UU) + d * UU + j] = cstate[idx];
}

// ---------------------------------------------------------------------------
extern "C" void kernel_launch(void* const* d_in, const int* in_sizes, int n_in,
                              void* d_out, int out_size, void* d_ws, size_t ws_size,
                              hipStream_t stream)
{
    const float* x  = (const float*)d_in[0];
    const float* Wf = (const float*)d_in[1];
    const float* Uf = (const float*)d_in[2];
    const float* bf = (const float*)d_in[3];
    const float* Wb = (const float*)d_in[4];
    const float* Ub = (const float*)d_in[5];
    const float* bb = (const float*)d_in[6];
    float* out = (float*)d_out;

    const size_t x16_bytes   = (size_t)BB * TT * FF * 2;             // 64 MiB
    const size_t wt_bytes    = (size_t)2 * NZ * FF * 2;              // 2 MiB
    const size_t upk_bytes   = (size_t)2 * 128 * 256 * sizeof(uint4);// 1 MiB
    const size_t state_bytes = (size_t)2 * BB * UU * sizeof(float);  // 128 KiB each
    const size_t hbuf_bytes  = (size_t)2 * 256 * 128 * 4;            // 256 KiB
    const size_t fixed = x16_bytes + wt_bytes + upk_bytes + 2 * state_bytes
                       + hbuf_bytes;

    int CT = TT;
    while (CT > 8) {
        size_t need = fixed + (size_t)2 * BB * CT * NZ * 2;
        if (need <= ws_size) break;
        CT >>= 1;
    }

    char* wsb = (char*)d_ws;
    _Float16* x16 = (_Float16*)wsb;
    _Float16* WT  = (_Float16*)(wsb + x16_bytes);
    uint4* Upkr2  = (uint4*)(wsb + x16_bytes + wt_bytes);
    float* hstate = (float*)(wsb + x16_bytes + wt_bytes + upk_bytes);
    float* cstate = hstate + 2 * BB * UU;
    unsigned int* hbuf = (unsigned int*)(wsb + x16_bytes + wt_bytes + upk_bytes
                                         + 2 * state_bytes);
    _Float16* xz16 = (_Float16*)(wsb + fixed);

    (void)hipFuncSetAttribute(reinterpret_cast<const void*>(enc_lstm_dual),
                              hipFuncAttributeMaxDynamicSharedMemorySize,
                              (int)LSTM_SHBYTES);

    enc_cast_x<<<4096, 256, 0, stream>>>(x, x16, BB * TT * FF / 4);
    enc_cast_wt<<<dim3(8, 16, 2), 256, 0, stream>>>(Wf, Wb, WT);
    enc_pack_u16v2<<<(2 * 128 * 256 + 255) / 256, 256, 0, stream>>>(Uf, Ub, Upkr2);
    enc_zero<<<(2 * 2 * BB * UU + 255) / 256, 256, 0, stream>>>(hstate, 2 * 2 * BB * UU);

    for (int c0 = 0; c0 < TT; c0 += CT) {
        dim3 ggrid((2 * BB * CT) / 128, NZ / 128);
        enc_gemm16<<<ggrid, 256, 0, stream>>>(x16, WT, bf, bb, xz16, c0, CT);
        enc_lstm_dual<<<128, 512, LSTM_SHBYTES, stream>>>(
            xz16, Upkr2, hstate, cstate, hbuf, out, c0, CT);
    }
    enc_final<<<(2 * BB * UU + 255) / 256, 256, 0, stream>>>(hstate, cstate, out);
}